// Round 7
// baseline (435.856 us; speedup 1.0000x reference)
//
#include <hip/hip_runtime.h>

// POMO decoder: B=64, N=500, E=128, H=8, D=16.
// Pipeline (R6, resubmitted R7 after infra timeout — no changes):
//   K0 mask_pack : float mask -> bitmask (attn only), in d_out head (dead region)
//   K1 gemm_mfma : q  = encF*WqF^T + encL*WqL^T   (split-bf16 MFMA) -> ws_q
//   K2 gemm_mfma : kv = encN*[Wk;Wv]^T            (split-bf16 MFMA) -> ws_kv
//   K3 attn_mfma : swapped-QK^T + bit-mask exp + cvt_pk/permlane + PV -> ws_att
//   K4 gemm_mfma : mh = att*Wc^T + bc             (split-bf16 MFMA) -> ws_mh (=ws_q)
//   K5 pointer_mfma : split-bf16 MFMA logits, tanh/exp epilogue, probabilities
//                  held in regs across all 8 g-passes, row-normalized in-register,
//                  single normalized store (no global round-trip).
// Numerics: split-bf16 (x=hi+lo, 3-term mfma) ~1e-5 rel err; softmax
// max-subtraction skipped (logits bounded); exp(-1e9) underflows to exact 0.
// R3 NOTE: no __launch_bounds__ occupancy floors (spill cascade).

#define B_ 64
#define N_ 500

typedef short bf16x8 __attribute__((ext_vector_type(8)));
typedef float f32x16 __attribute__((ext_vector_type(16)));
typedef unsigned short ushort8 __attribute__((ext_vector_type(8)));
typedef unsigned uint2v __attribute__((ext_vector_type(2)));

__device__ __forceinline__ float4 ld4(const float* p) { return *reinterpret_cast<const float4*>(p); }
__device__ __forceinline__ void st4(float* p, const float4 v) { *reinterpret_cast<float4*>(p) = v; }

__device__ __forceinline__ float fast_tanh(float x) {
    const float e = __expf(2.f * x);
    return 1.f - 2.f / (e + 1.f);
}
__device__ __forceinline__ unsigned short f2bf_rn(float x) {
    unsigned u = __float_as_uint(x);
    return (unsigned short)((u + 0x7FFFu + ((u >> 16) & 1u)) >> 16);
}
__device__ __forceinline__ float bf2f(unsigned short h) {
    return __uint_as_float(((unsigned)h) << 16);
}
__device__ __forceinline__ unsigned cvt_pk_bf16(float lo, float hi) {
    unsigned r;
    asm("v_cvt_pk_bf16_f32 %0, %1, %2" : "=v"(r) : "v"(lo), "v"(hi));
    return r;
}

// ---------------------------------------------------------------------------
// K0: pack float mask into bitmask (attn only): bit=1 means masked.
// ---------------------------------------------------------------------------
__global__ __launch_bounds__(256) void mask_pack(
    const float* __restrict__ mask, unsigned long long* __restrict__ bits)
{
    const int w = threadIdx.x >> 6, l = threadIdx.x & 63;
    const int n = blockIdx.x * 4 + w;
    const int b = blockIdx.y;
    const float* mrow = &mask[((size_t)b * N_ + n) * N_];
    unsigned long long* brow = &bits[((size_t)b * N_ + n) * 8];
#pragma unroll
    for (int c = 0; c < 8; ++c) {
        const int j = c * 64 + l;
        const bool pred = (j >= N_) || (mrow[min(j, N_ - 1)] < -1.f);
        const unsigned long long bal = __ballot(pred);
        if (l == 0) brow[c] = bal;
    }
}

// ---------------------------------------------------------------------------
// Split-bf16 MFMA GEMM (validated R4): C[M,F] = sum_t A_t * W_t^T (+bias).
// ---------------------------------------------------------------------------
__global__ __launch_bounds__(256) void gemm_mfma(
    const float* __restrict__ A1, const float* __restrict__ W1a, const float* __restrict__ W1b,
    const float* __restrict__ A2, const float* __restrict__ W2a, const float* __restrict__ W2b,
    const float* __restrict__ bias, float* __restrict__ C, const int F, const int nterm)
{
    __shared__ unsigned short Ah[64 * 128];
    __shared__ unsigned short Al[64 * 128];
    __shared__ unsigned short Wh[64 * 128];
    __shared__ unsigned short Wl[64 * 128];

    const int t  = threadIdx.x;
    const int rb = blockIdx.y * 64;
    const int fb = blockIdx.x * 64;
    const int l  = t & 63;
    const int w  = t >> 6;
    const int half = l >> 5;
    const int mrow = 32 * (w >> 1) + (l & 31);
    const int ncol = 32 * (w & 1) + (l & 31);
    const int sr  = t >> 2;
    const int sc0 = (t & 3) * 32;

    f32x16 acc;
#pragma unroll
    for (int i = 0; i < 16; ++i) acc[i] = 0.f;

    for (int tt = 0; tt < nterm; ++tt) {
        const float* A  = tt ? A2 : A1;
        const float* Wa = tt ? W2a : W1a;
        const float* Wb = tt ? W2b : W1b;
        const float* W  = (fb < 128) ? Wa : Wb;
        const int frbase = fb & 127;

        if (tt) __syncthreads();

#pragma unroll
        for (int it = 0; it < 4; ++it) {
            const int c = sc0 + it * 8;
            const int chunk = c >> 3;
            const int dstA = sr * 128 + ((chunk ^ (sr & 7)) << 3);
            {
                const float4 v0 = ld4(&A[(size_t)(rb + sr) * 128 + c]);
                const float4 v1 = ld4(&A[(size_t)(rb + sr) * 128 + c + 4]);
                const float f[8] = {v0.x, v0.y, v0.z, v0.w, v1.x, v1.y, v1.z, v1.w};
                ushort8 hi, lo;
#pragma unroll
                for (int e = 0; e < 8; ++e) {
                    const unsigned short h = f2bf_rn(f[e]);
                    hi[e] = h;
                    lo[e] = f2bf_rn(f[e] - bf2f(h));
                }
                *reinterpret_cast<ushort8*>(&Ah[dstA]) = hi;
                *reinterpret_cast<ushort8*>(&Al[dstA]) = lo;
            }
            {
                const float4 v0 = ld4(&W[(size_t)(frbase + sr) * 128 + c]);
                const float4 v1 = ld4(&W[(size_t)(frbase + sr) * 128 + c + 4]);
                const float f[8] = {v0.x, v0.y, v0.z, v0.w, v1.x, v1.y, v1.z, v1.w};
                ushort8 hi, lo;
#pragma unroll
                for (int e = 0; e < 8; ++e) {
                    const unsigned short h = f2bf_rn(f[e]);
                    hi[e] = h;
                    lo[e] = f2bf_rn(f[e] - bf2f(h));
                }
                *reinterpret_cast<ushort8*>(&Wh[dstA]) = hi;
                *reinterpret_cast<ushort8*>(&Wl[dstA]) = lo;
            }
        }
        __syncthreads();

#pragma unroll
        for (int ks = 0; ks < 8; ++ks) {
            const int chA = (2 * ks + half) ^ (mrow & 7);
            const int chW = (2 * ks + half) ^ (ncol & 7);
            const bf16x8 ah = *reinterpret_cast<const bf16x8*>(&Ah[mrow * 128 + chA * 8]);
            const bf16x8 al = *reinterpret_cast<const bf16x8*>(&Al[mrow * 128 + chA * 8]);
            const bf16x8 wh = *reinterpret_cast<const bf16x8*>(&Wh[ncol * 128 + chW * 8]);
            const bf16x8 wl = *reinterpret_cast<const bf16x8*>(&Wl[ncol * 128 + chW * 8]);
            acc = __builtin_amdgcn_mfma_f32_32x32x16_bf16(ah, wh, acc, 0, 0, 0);
            acc = __builtin_amdgcn_mfma_f32_32x32x16_bf16(ah, wl, acc, 0, 0, 0);
            acc = __builtin_amdgcn_mfma_f32_32x32x16_bf16(al, wh, acc, 0, 0, 0);
        }
    }

    const int col = fb + ncol;
    const float bv = bias ? bias[col] : 0.f;
#pragma unroll
    for (int r = 0; r < 16; ++r) {
        const int row = rb + 32 * (w >> 1) + (r & 3) + 8 * (r >> 2) + 4 * half;
        C[(size_t)row * F + col] = acc[r] + bv;
    }
}

// ---------------------------------------------------------------------------
// K3: MFMA attention (validated R5, unchanged)
// ---------------------------------------------------------------------------
__global__ __launch_bounds__(256) void attn_mfma(
    const float* __restrict__ q, const float* __restrict__ kv,
    const unsigned* __restrict__ bits, float* __restrict__ att)
{
    __shared__ __align__(16) unsigned short Kh[32 * 16];
    __shared__ __align__(16) unsigned short Kl[32 * 16];
    __shared__ __align__(16) unsigned short Vh[32 * 40];
    __shared__ __align__(16) unsigned short Vl[32 * 40];
    __shared__ float Rinv[4][32];

    const int t  = threadIdx.x;
    const int w  = t >> 6;
    const int l  = t & 63;
    const int lr = l & 31;
    const int h  = l >> 5;
    const int rt = blockIdx.x;
    const int hh = blockIdx.y;
    const int b  = blockIdx.z;

    const int r_base = rt * 128 + w * 32;
    const int rc = min(r_base + lr, N_ - 1);

    bf16x8 qh, ql;
    {
        const float* qp = &q[((size_t)(b * N_ + rc)) * 128 + hh * 16 + 8 * h];
        const float4 a = ld4(qp), c = ld4(qp + 4);
        const float f[8] = {a.x, a.y, a.z, a.w, c.x, c.y, c.z, c.w};
#pragma unroll
        for (int e = 0; e < 8; ++e) {
            const float v = f[e] * 0.25f;
            const unsigned short hi = f2bf_rn(v);
            qh[e] = (short)hi;
            ql[e] = (short)f2bf_rn(v - bf2f(hi));
        }
    }

    const int sj   = t >> 3;
    const int sd   = (t & 7) * 2;
    const int kswz = sd ^ (8 * ((sj >> 2) & 1));
    const int vd   = t & 15;
    const int vj2  = (t >> 4) * 2;

    const f32x16 z = {0.f};
    f32x16 out;
#pragma unroll
    for (int i = 0; i < 16; ++i) out[i] = 0.f;
    float rowsum = 0.f;

    const unsigned* brow = &bits[(size_t)(b * N_ + rc) * 16];
    const int kchunk = h ^ ((lr >> 2) & 1);

    for (int js = 0; js < 16; ++js) {
        const int j0 = js * 32;
        __syncthreads();
        {
            const int jg = min(j0 + sj, N_ - 1);
            const float2 kk = *reinterpret_cast<const float2*>(
                &kv[((size_t)(b * N_ + jg)) * 256 + hh * 16 + sd]);
            const unsigned short h0 = f2bf_rn(kk.x), h1 = f2bf_rn(kk.y);
            const unsigned short l0 = f2bf_rn(kk.x - bf2f(h0)), l1 = f2bf_rn(kk.y - bf2f(h1));
            *reinterpret_cast<unsigned*>(&Kh[sj * 16 + kswz]) = (unsigned)h0 | ((unsigned)h1 << 16);
            *reinterpret_cast<unsigned*>(&Kl[sj * 16 + kswz]) = (unsigned)l0 | ((unsigned)l1 << 16);
        }
        {
            const int jg0 = min(j0 + vj2, N_ - 1), jg1 = min(j0 + vj2 + 1, N_ - 1);
            const float v0 = kv[((size_t)(b * N_ + jg0)) * 256 + 128 + hh * 16 + vd];
            const float v1 = kv[((size_t)(b * N_ + jg1)) * 256 + 128 + hh * 16 + vd];
            const unsigned short h0 = f2bf_rn(v0), h1 = f2bf_rn(v1);
            const unsigned short l0 = f2bf_rn(v0 - bf2f(h0)), l1 = f2bf_rn(v1 - bf2f(h1));
            *reinterpret_cast<unsigned*>(&Vh[vd * 40 + vj2]) = (unsigned)h0 | ((unsigned)h1 << 16);
            *reinterpret_cast<unsigned*>(&Vl[vd * 40 + vj2]) = (unsigned)l0 | ((unsigned)l1 << 16);
        }
        __syncthreads();

        const bf16x8 kfh = *reinterpret_cast<const bf16x8*>(&Kh[lr * 16 + kchunk * 8]);
        const bf16x8 kfl = *reinterpret_cast<const bf16x8*>(&Kl[lr * 16 + kchunk * 8]);
        f32x16 st = __builtin_amdgcn_mfma_f32_32x32x16_bf16(kfh, qh, z, 0, 0, 0);
        st = __builtin_amdgcn_mfma_f32_32x32x16_bf16(kfh, ql, st, 0, 0, 0);
        st = __builtin_amdgcn_mfma_f32_32x32x16_bf16(kfl, qh, st, 0, 0, 0);

        const unsigned bw = brow[js];
        float p[16];
#pragma unroll
        for (int g = 0; g < 16; ++g) {
            const int crow = (g & 3) + 8 * (g >> 2) + 4 * h;
            const float e = __expf(st[g]);
            p[g] = ((bw >> crow) & 1u) ? 0.f : e;
            rowsum += p[g];
        }

        unsigned wH[8], wL[8];
#pragma unroll
        for (int i = 0; i < 8; ++i) {
            wH[i] = cvt_pk_bf16(p[2 * i], p[2 * i + 1]);
            const float r0 = p[2 * i]     - __uint_as_float(wH[i] << 16);
            const float r1 = p[2 * i + 1] - __uint_as_float(wH[i] & 0xffff0000u);
            wL[i] = cvt_pk_bf16(r0, r1);
        }

        const uint2v aH0 = __builtin_amdgcn_permlane32_swap(wH[0], wH[2], false, false);
        const uint2v bH0 = __builtin_amdgcn_permlane32_swap(wH[1], wH[3], false, false);
        const uint2v aH1 = __builtin_amdgcn_permlane32_swap(wH[4], wH[6], false, false);
        const uint2v bH1 = __builtin_amdgcn_permlane32_swap(wH[5], wH[7], false, false);
        const uint2v aL0 = __builtin_amdgcn_permlane32_swap(wL[0], wL[2], false, false);
        const uint2v bL0 = __builtin_amdgcn_permlane32_swap(wL[1], wL[3], false, false);
        const uint2v aL1 = __builtin_amdgcn_permlane32_swap(wL[4], wL[6], false, false);
        const uint2v bL1 = __builtin_amdgcn_permlane32_swap(wL[5], wL[7], false, false);
        union { unsigned u[4]; bf16x8 v; } pH0 = {{aH0[0], bH0[0], aH0[1], bH0[1]}};
        union { unsigned u[4]; bf16x8 v; } pH1 = {{aH1[0], bH1[0], aH1[1], bH1[1]}};
        union { unsigned u[4]; bf16x8 v; } pL0 = {{aL0[0], bL0[0], aL0[1], bL0[1]}};
        union { unsigned u[4]; bf16x8 v; } pL1 = {{aL1[0], bL1[0], aL1[1], bL1[1]}};

        const bf16x8 vh0 = *reinterpret_cast<const bf16x8*>(&Vh[lr * 40 + 0 * 16 + 8 * h]);
        const bf16x8 vl0 = *reinterpret_cast<const bf16x8*>(&Vl[lr * 40 + 0 * 16 + 8 * h]);
        const bf16x8 vh1 = *reinterpret_cast<const bf16x8*>(&Vh[lr * 40 + 1 * 16 + 8 * h]);
        const bf16x8 vl1 = *reinterpret_cast<const bf16x8*>(&Vl[lr * 40 + 1 * 16 + 8 * h]);
        out = __builtin_amdgcn_mfma_f32_32x32x16_bf16(pH0.v, vh0, out, 0, 0, 0);
        out = __builtin_amdgcn_mfma_f32_32x32x16_bf16(pL0.v, vh0, out, 0, 0, 0);
        out = __builtin_amdgcn_mfma_f32_32x32x16_bf16(pH0.v, vl0, out, 0, 0, 0);
        out = __builtin_amdgcn_mfma_f32_32x32x16_bf16(pH1.v, vh1, out, 0, 0, 0);
        out = __builtin_amdgcn_mfma_f32_32x32x16_bf16(pL1.v, vh1, out, 0, 0, 0);
        out = __builtin_amdgcn_mfma_f32_32x32x16_bf16(pH1.v, vl1, out, 0, 0, 0);
    }

    rowsum += __shfl_xor(rowsum, 32, 64);
    if (h == 0) Rinv[w][lr] = 1.f / rowsum;
    const float4 i0 = *reinterpret_cast<const float4*>(&Rinv[w][4 * h]);
    const float4 i1 = *reinterpret_cast<const float4*>(&Rinv[w][8 + 4 * h]);
    const float4 i2 = *reinterpret_cast<const float4*>(&Rinv[w][16 + 4 * h]);
    const float4 i3 = *reinterpret_cast<const float4*>(&Rinv[w][24 + 4 * h]);
    const float iv[16] = {i0.x, i0.y, i0.z, i0.w, i1.x, i1.y, i1.z, i1.w,
                          i2.x, i2.y, i2.z, i2.w, i3.x, i3.y, i3.z, i3.w};
    if (lr < 16) {
#pragma unroll
        for (int g = 0; g < 16; ++g) {
            const int row = r_base + (g & 3) + 8 * (g >> 2) + 4 * h;
            if (row < N_)
                att[((size_t)(b * N_ + row)) * 128 + hh * 16 + lr] = out[g] * iv[g];
        }
    }
}

// ---------------------------------------------------------------------------
// K5 (R6): pointer via split-bf16 MFMA. Block = 64 rows x 500 g (8 passes of
// 64 g). mh tile staged/split ONCE; enc tile per pass. Probabilities held in
// registers across passes (f32x16 p[8], statically indexed), row-normalized
// in-register, single normalized store — no global round-trip.
// ---------------------------------------------------------------------------
__global__ __launch_bounds__(256) void pointer_mfma(
    const float* __restrict__ mh, const float* __restrict__ enc,
    const float* __restrict__ mask, float* __restrict__ outp)
{
    __shared__ unsigned short Mh[64 * 128];
    __shared__ unsigned short Ml[64 * 128];
    __shared__ unsigned short Eh[64 * 128];
    __shared__ unsigned short El[64 * 128];
    __shared__ float Rpart[4][32];
    __shared__ float RinvS[64];

    const int t  = threadIdx.x;
    const int rt = blockIdx.x;
    const int b  = blockIdx.y;
    const int l  = t & 63;
    const int w  = t >> 6;
    const int half = l >> 5;
    const int mrow = 32 * (w >> 1) + (l & 31);   // block-local A row
    const int ncol = 32 * (w & 1) + (l & 31);    // block-local g (0..63)
    const int sr  = t >> 2;
    const int sc0 = (t & 3) * 32;
    const int ch7 = l & 7;                       // (mrow&7) == (ncol&7) == l&7

    // ---- stage + split mh tile once
#pragma unroll
    for (int it = 0; it < 4; ++it) {
        const int c = sc0 + it * 8;
        const int dst = sr * 128 + ((((c >> 3)) ^ (sr & 7)) << 3);
        const float4 v0 = ld4(&mh[(size_t)(b * N_ + min(rt * 64 + sr, N_ - 1)) * 128 + c]);
        const float4 v1 = ld4(&mh[(size_t)(b * N_ + min(rt * 64 + sr, N_ - 1)) * 128 + c + 4]);
        const float f[8] = {v0.x, v0.y, v0.z, v0.w, v1.x, v1.y, v1.z, v1.w};
        ushort8 hi, lo;
#pragma unroll
        for (int e = 0; e < 8; ++e) {
            const unsigned short hv = f2bf_rn(f[e]);
            hi[e] = hv;
            lo[e] = f2bf_rn(f[e] - bf2f(hv));
        }
        *reinterpret_cast<ushort8*>(&Mh[dst]) = hi;
        *reinterpret_cast<ushort8*>(&Ml[dst]) = lo;
    }

    f32x16 p[8];
    f32x16 racc;
#pragma unroll
    for (int i = 0; i < 16; ++i) racc[i] = 0.f;

    const float cinv = 0.08838834764831845f;  // 1/sqrt(128)

#pragma unroll
    for (int pass = 0; pass < 8; ++pass) {
        __syncthreads();  // pass 0: mh staged; else: prior Eh reads done
        // ---- stage + split enc tile rows [pass*64 + sr]
#pragma unroll
        for (int it = 0; it < 4; ++it) {
            const int c = sc0 + it * 8;
            const int dst = sr * 128 + ((((c >> 3)) ^ (sr & 7)) << 3);
            const int gg = min(pass * 64 + sr, N_ - 1);
            const float4 v0 = ld4(&enc[(size_t)(b * N_ + gg) * 128 + c]);
            const float4 v1 = ld4(&enc[(size_t)(b * N_ + gg) * 128 + c + 4]);
            const float f[8] = {v0.x, v0.y, v0.z, v0.w, v1.x, v1.y, v1.z, v1.w};
            ushort8 hi, lo;
#pragma unroll
            for (int e = 0; e < 8; ++e) {
                const unsigned short hv = f2bf_rn(f[e]);
                hi[e] = hv;
                lo[e] = f2bf_rn(f[e] - bf2f(hv));
            }
            *reinterpret_cast<ushort8*>(&Eh[dst]) = hi;
            *reinterpret_cast<ushort8*>(&El[dst]) = lo;
        }
        __syncthreads();

        // ---- 8 k-steps x 3 split-mfma
        f32x16 acc;
#pragma unroll
        for (int i = 0; i < 16; ++i) acc[i] = 0.f;
#pragma unroll
        for (int ks = 0; ks < 8; ++ks) {
            const int ch = (2 * ks + half) ^ ch7;
            const bf16x8 ah = *reinterpret_cast<const bf16x8*>(&Mh[mrow * 128 + ch * 8]);
            const bf16x8 al = *reinterpret_cast<const bf16x8*>(&Ml[mrow * 128 + ch * 8]);
            const bf16x8 eh = *reinterpret_cast<const bf16x8*>(&Eh[ncol * 128 + ch * 8]);
            const bf16x8 el = *reinterpret_cast<const bf16x8*>(&El[ncol * 128 + ch * 8]);
            acc = __builtin_amdgcn_mfma_f32_32x32x16_bf16(ah, eh, acc, 0, 0, 0);
            acc = __builtin_amdgcn_mfma_f32_32x32x16_bf16(ah, el, acc, 0, 0, 0);
            acc = __builtin_amdgcn_mfma_f32_32x32x16_bf16(al, eh, acc, 0, 0, 0);
        }

        // ---- epilogue: tanh-clip + mask + exp; accumulate row sums
        const int g = pass * 64 + ncol;
#pragma unroll
        for (int r = 0; r < 16; ++r) {
            const int gr = rt * 64 + 32 * (w >> 1) + (r & 3) + 8 * (r >> 2) + 4 * half;
            float mv = -1e9f;
            if (gr < N_ && g < N_) mv = mask[((size_t)b * N_ + gr) * N_ + g];
            const float pv = __expf(10.f * fast_tanh(acc[r] * cinv) + mv);
            p[pass][r] = pv;
            racc[r] += pv;
        }
    }

    // ---- row sums: reduce over 32 lanes (same half = same rows)
#pragma unroll
    for (int m = 1; m <= 16; m <<= 1)
#pragma unroll
        for (int r = 0; r < 16; ++r) racc[r] += __shfl_xor(racc[r], m, 64);

    if ((l & 31) == 0) {
#pragma unroll
        for (int r = 0; r < 16; ++r)
            Rpart[w][(r & 3) + 8 * (r >> 2) + 4 * half] = racc[r];
    }
    __syncthreads();
    if (t < 64) {
        const int hi = t >> 5, R = t & 31;
        RinvS[t] = 1.f / (Rpart[2 * hi][R] + Rpart[2 * hi + 1][R]);
    }
    __syncthreads();

    // ---- normalized store (single write)
#pragma unroll
    for (int pass = 0; pass < 8; ++pass) {
        const int g = pass * 64 + ncol;
#pragma unroll
        for (int r = 0; r < 16; ++r) {
            const int br = 32 * (w >> 1) + (r & 3) + 8 * (r >> 2) + 4 * half;
            const int gr = rt * 64 + br;
            if (gr < N_ && g < N_)
                outp[((size_t)b * N_ + gr) * N_ + g] = p[pass][r] * RinvS[br];
        }
    }
}

extern "C" void kernel_launch(void* const* d_in, const int* in_sizes, int n_in,
                              void* d_out, int out_size, void* d_ws, size_t ws_size,
                              hipStream_t stream) {
    const float* enc  = (const float*)d_in[0];
    const float* encf = (const float*)d_in[1];
    const float* encl = (const float*)d_in[2];
    const float* mask = (const float*)d_in[3];
    const float* Wqf  = (const float*)d_in[4];
    const float* Wql  = (const float*)d_in[5];
    const float* Wk   = (const float*)d_in[6];
    const float* Wv   = (const float*)d_in[7];
    const float* Wc   = (const float*)d_in[8];
    const float* bc   = (const float*)d_in[9];
    float* out = (float*)d_out;
    float* ws = (float*)d_ws;

    float* ws_q    = ws;              // [32000,128]
    float* ws_kv   = ws + 4096000;    // [32000,256]
    float* ws_att  = ws + 12288000;   // [32000,128]
    float* ws_mh   = ws_q;            // q dead after attn

    // bitmask scratch in d_out head (attn only; d_out rewritten by pointer)
    unsigned long long* bits64 = (unsigned long long*)d_out;

    mask_pack<<<dim3(125, 64), 256, 0, stream>>>(mask, bits64);
    gemm_mfma<<<dim3(2, 500), 256, 0, stream>>>(encf, Wqf, nullptr, encl, Wql, nullptr,
                                                nullptr, ws_q, 128, 2);
    gemm_mfma<<<dim3(4, 500), 256, 0, stream>>>(enc, Wk, Wv, nullptr, nullptr, nullptr,
                                                nullptr, ws_kv, 256, 1);
    attn_mfma<<<dim3(4, 8, 64), 256, 0, stream>>>(ws_q, ws_kv, (const unsigned*)d_out, ws_att);
    gemm_mfma<<<dim3(2, 500), 256, 0, stream>>>(ws_att, Wc, nullptr, nullptr, nullptr, nullptr,
                                                bc, ws_mh, 128, 1);
    pointer_mfma<<<dim3(8, 64), 256, 0, stream>>>(ws_mh, enc, mask, out);
}